// Round 1
// baseline (761.609 us; speedup 1.0000x reference)
//
#include <hip/hip_runtime.h>
#include <stdint.h>

#define NN 50000
#define NE 800000
// dims: layer1 in=128 out=256, layer2 in=256 out=128

// ---------------- edge dtype detector ----------------
// Reference says int64; harness doc says int*. Detect at runtime:
// if stored as int64 (little-endian, values < 2^31), every odd 32-bit word
// of the first 512 pairs is 0. If int32, odd words are real node ids
// (all-zero probability ~ (1/50000)^256 ~ 0).
__global__ void detect_kernel(const int* __restrict__ edges, int* __restrict__ flag) {
    __shared__ int nz;
    if (threadIdx.x == 0) nz = 0;
    __syncthreads();
    for (int i = threadIdx.x; i < 512; i += blockDim.x) {
        if (edges[2 * i + 1] != 0) atomicOr(&nz, 1);
    }
    __syncthreads();
    if (threadIdx.x == 0) *flag = nz ? 0 : 1;  // 1 => int64 storage
}

// ---------------- CSR build ----------------
__global__ void hist_kernel(const int* __restrict__ edges, const int* __restrict__ flag,
                            int* __restrict__ counts, int E) {
    int f = *flag;
    int e = blockIdx.x * blockDim.x + threadIdx.x;
    if (e < E) {
        int d = edges[(size_t)(E + e) << f];
        atomicAdd(&counts[d], 1);
    }
}

__global__ void scan_kernel(const int* __restrict__ counts, int* __restrict__ row_start,
                            int* __restrict__ cursor, int N) {
    __shared__ int buf[1024];
    __shared__ int carry;
    int tid = threadIdx.x;
    if (tid == 0) carry = 0;
    __syncthreads();
    for (int base = 0; base < N; base += 1024) {
        int v = (base + tid < N) ? counts[base + tid] : 0;
        buf[tid] = v;
        __syncthreads();
        for (int off = 1; off < 1024; off <<= 1) {
            int t = (tid >= off) ? buf[tid - off] : 0;
            __syncthreads();
            buf[tid] += t;
            __syncthreads();
        }
        int incl = buf[tid];
        int excl = incl - v;
        if (base + tid < N) {
            row_start[base + tid] = carry + excl;
            cursor[base + tid]    = carry + excl;
        }
        int total = buf[1023];
        __syncthreads();
        if (tid == 0) carry += total;
        __syncthreads();
    }
    if (threadIdx.x == 0) row_start[N] = carry;
}

__global__ void fill_kernel(const int* __restrict__ edges, const int* __restrict__ flag,
                            int* __restrict__ cursor, int* __restrict__ edge_src, int E) {
    int f = *flag;
    int e = blockIdx.x * blockDim.x + threadIdx.x;
    if (e < E) {
        int s = edges[(size_t)e << f];
        int d = edges[(size_t)(E + e) << f];
        int pos = atomicAdd(&cursor[d], 1);
        edge_src[pos] = s;
    }
}

// ---------------- mean aggregation: one block per node, thread = feature ----------------
__global__ void agg_kernel(const float* __restrict__ X, const int* __restrict__ row_start,
                           const int* __restrict__ edge_src, float* __restrict__ mean, int D) {
    int n = blockIdx.x;
    int t = threadIdx.x;
    int start = row_start[n], end = row_start[n + 1];
    float acc = 0.f;
    for (int i = start; i < end; ++i) {
        int s = edge_src[i];
        acc += X[(size_t)s * D + t];
    }
    int deg = end - start;
    float inv = 1.0f / (float)(deg > 1 ? deg : 1);
    mean[(size_t)n * D + t] = acc * inv;
}

// ---------------- fused SAGE GEMM: C = [A1 ‖ A2] @ [Wl ‖ Wr]^T + b (opt relu) ----------------
// A1,A2: [N,K] row-major; Wl,Wr: [OUT,K] row-major; C: [N,OUT]
__global__ __launch_bounds__(256) void gemm_fused(
    const float* __restrict__ A1, const float* __restrict__ A2,
    const float* __restrict__ Wl, const float* __restrict__ Wr,
    const float* __restrict__ bias, float* __restrict__ C,
    int N, int K, int OUT, int relu) {
    __shared__ float As[16][68];  // [k][m], stride 68 keeps float4 alignment, 2-way-max conflicts
    __shared__ float Ws[16][68];  // [k][n]
    int tid = threadIdx.x;
    int tx = tid & 15, ty = tid >> 4;
    int row0 = blockIdx.x * 64, col0 = blockIdx.y * 64;
    float acc[4][4] = {};
    int lk = tid & 15, lr = tid >> 4;

    for (int kb = 0; kb < 2 * K; kb += 16) {
        int gk = kb + lk;
#pragma unroll
        for (int p = 0; p < 4; ++p) {
            int r = lr + 16 * p;
            int grow = row0 + r;
            float v = 0.f;
            if (grow < N) {
                v = (gk < K) ? A1[(size_t)grow * K + gk]
                             : A2[(size_t)grow * K + (gk - K)];
            }
            As[lk][r] = v;
            int gcol = col0 + r;  // OUT divisible by 64 -> always in range
            float w = (gk < K) ? Wl[(size_t)gcol * K + gk]
                               : Wr[(size_t)gcol * K + (gk - K)];
            Ws[lk][r] = w;
        }
        __syncthreads();
#pragma unroll
        for (int kk = 0; kk < 16; ++kk) {
            float4 a4 = *(const float4*)&As[kk][ty * 4];
            float4 b4 = *(const float4*)&Ws[kk][tx * 4];
            float av[4] = {a4.x, a4.y, a4.z, a4.w};
            float bv[4] = {b4.x, b4.y, b4.z, b4.w};
#pragma unroll
            for (int i = 0; i < 4; ++i)
#pragma unroll
                for (int j = 0; j < 4; ++j) acc[i][j] += av[i] * bv[j];
        }
        __syncthreads();
    }

    float4 b4 = *(const float4*)&bias[col0 + tx * 4];
    float bb[4] = {b4.x, b4.y, b4.z, b4.w};
#pragma unroll
    for (int i = 0; i < 4; ++i) {
        int m = row0 + ty * 4 + i;
        if (m < N) {
            float4 o;
            float* op = &o.x;
#pragma unroll
            for (int j = 0; j < 4; ++j) {
                float v = acc[i][j] + bb[j];
                if (relu) v = fmaxf(v, 0.f);
                op[j] = v;
            }
            *(float4*)&C[(size_t)m * OUT + col0 + tx * 4] = o;
        }
    }
}

extern "C" void kernel_launch(void* const* d_in, const int* in_sizes, int n_in,
                              void* d_out, int out_size, void* d_ws, size_t ws_size,
                              hipStream_t stream) {
    const float* x    = (const float*)d_in[0];
    const int*   edges = (const int*)d_in[1];
    const float* W1_l = (const float*)d_in[2];
    const float* b1   = (const float*)d_in[3];
    const float* W1_r = (const float*)d_in[4];
    const float* W2_l = (const float*)d_in[5];
    const float* b2   = (const float*)d_in[6];
    const float* W2_r = (const float*)d_in[7];
    float* out = (float*)d_out;

    const int N = NN, E = NE;
    auto align256 = [](size_t v) { return (v + 255) & ~(size_t)255; };
    char* ws = (char*)d_ws;
    size_t o = 0;
    int* flag      = (int*)(ws + o); o += 256;
    int* counts    = (int*)(ws + o); o += align256((size_t)N * 4);
    int* row_start = (int*)(ws + o); o += align256((size_t)(N + 1) * 4);
    int* cursor    = (int*)(ws + o); o += align256((size_t)N * 4);
    int* edge_src  = (int*)(ws + o); o += align256((size_t)E * 4);
    float* meanbuf = (float*)(ws + o); o += align256((size_t)N * 256 * 4);  // mean1 [N,128] then mean2 [N,256]
    float* h       = (float*)(ws + o); o += align256((size_t)N * 256 * 4);

    hipMemsetAsync(counts, 0, (size_t)N * 4, stream);
    detect_kernel<<<1, 256, 0, stream>>>(edges, flag);
    hist_kernel<<<(E + 255) / 256, 256, 0, stream>>>(edges, flag, counts, E);
    scan_kernel<<<1, 1024, 0, stream>>>(counts, row_start, cursor, N);
    fill_kernel<<<(E + 255) / 256, 256, 0, stream>>>(edges, flag, cursor, edge_src, E);

    // layer 1: mean1 = mean_agg(x) [N,128]; h = relu([mean1‖x] @ [W1_l‖W1_r]^T + b1) [N,256]
    agg_kernel<<<N, 128, 0, stream>>>(x, row_start, edge_src, meanbuf, 128);
    {
        dim3 grid((N + 63) / 64, 256 / 64);
        gemm_fused<<<grid, 256, 0, stream>>>(meanbuf, x, W1_l, W1_r, b1, h, N, 128, 256, 1);
    }
    // layer 2: mean2 = mean_agg(h) [N,256]; out = [mean2‖h] @ [W2_l‖W2_r]^T + b2 [N,128]
    agg_kernel<<<N, 256, 0, stream>>>(h, row_start, edge_src, meanbuf, 256);
    {
        dim3 grid((N + 63) / 64, 128 / 64);
        gemm_fused<<<grid, 256, 0, stream>>>(meanbuf, h, W2_l, W2_r, b2, out, N, 256, 128, 0);
    }
}

// Round 2
// 414.661 us; speedup vs baseline: 1.8367x; 1.8367x over previous
//
#include <hip/hip_runtime.h>
#include <stdint.h>

#define NN 50000
#define NE 800000
// layer1: in=128 hid=256; layer2: in=256 out=128
// Layer-2 restructured: out = mean_agg(h @ W2_l^T) + (h @ W2_r^T + b2)
// (mean commutes with the linear map; aggregate the 128-dim projection, not 256-dim h)

typedef __bf16 bf16x8 __attribute__((ext_vector_type(8)));
typedef float  f32x4  __attribute__((ext_vector_type(4)));

__device__ __forceinline__ unsigned short f2bf(float f) {
    unsigned int u = __float_as_uint(f);
    unsigned int r = (u + 0x7fffu + ((u >> 16) & 1u)) >> 16;   // RNE
    return (unsigned short)r;
}
__device__ __forceinline__ float bf_lo(unsigned int v) { return __uint_as_float(v << 16); }
__device__ __forceinline__ float bf_hi(unsigned int v) { return __uint_as_float(v & 0xffff0000u); }

// ---------------- edge dtype detector (int64 vs int32 storage) ----------------
__global__ void detect_kernel(const int* __restrict__ edges, int* __restrict__ flag) {
    __shared__ int nz;
    if (threadIdx.x == 0) nz = 0;
    __syncthreads();
    for (int i = threadIdx.x; i < 512; i += blockDim.x)
        if (edges[2 * i + 1] != 0) atomicOr(&nz, 1);
    __syncthreads();
    if (threadIdx.x == 0) *flag = nz ? 0 : 1;  // 1 => int64 storage
}

// ---------------- CSR build ----------------
__global__ void hist_kernel(const int* __restrict__ edges, const int* __restrict__ flag,
                            int* __restrict__ counts, int E) {
    int f = *flag;
    int e = blockIdx.x * blockDim.x + threadIdx.x;
    if (e < E) atomicAdd(&counts[edges[(size_t)(E + e) << f]], 1);
}

// hierarchical exclusive scan over counts[N]
__global__ void scan1_kernel(const int* __restrict__ counts, int* __restrict__ partial,
                             int* __restrict__ bsum, int N) {
    __shared__ int buf[256];
    int tid = threadIdx.x;
    int g = blockIdx.x * 256 + tid;
    int v = (g < N) ? counts[g] : 0;
    buf[tid] = v;
    __syncthreads();
    for (int off = 1; off < 256; off <<= 1) {
        int t = (tid >= off) ? buf[tid - off] : 0;
        __syncthreads();
        buf[tid] += t;
        __syncthreads();
    }
    if (g < N) partial[g] = buf[tid] - v;
    if (tid == 255) bsum[blockIdx.x] = buf[255];
}

__global__ void scan2_kernel(const int* __restrict__ bsum, int* __restrict__ boff, int nb) {
    __shared__ int buf[256];
    int tid = threadIdx.x;
    int v = (tid < nb) ? bsum[tid] : 0;
    buf[tid] = v;
    __syncthreads();
    for (int off = 1; off < 256; off <<= 1) {
        int t = (tid >= off) ? buf[tid - off] : 0;
        __syncthreads();
        buf[tid] += t;
        __syncthreads();
    }
    if (tid < nb) boff[tid] = buf[tid] - v;
    if (tid == 0) boff[nb] = buf[255];   // total
}

__global__ void scan3_kernel(const int* __restrict__ partial, const int* __restrict__ boff,
                             int* __restrict__ row_start, int* __restrict__ cursor,
                             int N, int nb) {
    int g = blockIdx.x * 256 + threadIdx.x;
    if (g < N) {
        int v = partial[g] + boff[g >> 8];
        row_start[g] = v;
        cursor[g] = v;
    }
    if (g == 0) row_start[N] = boff[nb];
}

__global__ void fill_kernel(const int* __restrict__ edges, const int* __restrict__ flag,
                            int* __restrict__ cursor, int* __restrict__ edge_src, int E) {
    int f = *flag;
    int e = blockIdx.x * blockDim.x + threadIdx.x;
    if (e < E) {
        int s = edges[(size_t)e << f];
        int d = edges[(size_t)(E + e) << f];
        edge_src[atomicAdd(&cursor[d], 1)] = s;
    }
}

// ---------------- casts / weight packing ----------------
__global__ void cast_x_kernel(const float* __restrict__ in, unsigned short* __restrict__ out, int n2) {
    int i = blockIdx.x * blockDim.x + threadIdx.x;   // one per pair
    if (i < n2) {
        float2 v = *(const float2*)(in + 2 * (size_t)i);
        unsigned int p = (unsigned int)f2bf(v.x) | ((unsigned int)f2bf(v.y) << 16);
        *(unsigned int*)(out + 2 * (size_t)i) = p;
    }
}

// B1[o][k] (o,k in [0,256)): k<128 -> W1_l[o,k], else W1_r[o,k-128]
__global__ void packB1_kernel(const float* __restrict__ Wl, const float* __restrict__ Wr,
                              unsigned short* __restrict__ B) {
    int idx = blockIdx.x * 256 + threadIdx.x;
    int o = idx >> 8, k = idx & 255;
    float v = (k < 128) ? Wl[o * 128 + k] : Wr[o * 128 + (k - 128)];
    B[idx] = f2bf(v);
}
// B2[o][k]: o<128 -> W2_l[o,k], else W2_r[o-128,k]  (k in [0,256))
__global__ void packB2_kernel(const float* __restrict__ Wl, const float* __restrict__ Wr,
                              unsigned short* __restrict__ B) {
    int idx = blockIdx.x * 256 + threadIdx.x;
    int o = idx >> 8, k = idx & 255;
    float v = (o < 128) ? Wl[o * 256 + k] : Wr[(o - 128) * 256 + k];
    B[idx] = f2bf(v);
}

// ---------------- mean aggregation over bf16 rows of width 128 ----------------
// 1 wave per node (64 lanes x bf16x2 = 128 features), 4 nodes per block.
__global__ __launch_bounds__(256) void agg1_kernel(
    const unsigned short* __restrict__ X, const int* __restrict__ row_start,
    const int* __restrict__ edge_src, unsigned short* __restrict__ mean) {
    int node = blockIdx.x * 4 + (threadIdx.x >> 6);
    int lane = threadIdx.x & 63;
    if (node >= NN) return;
    int s0 = row_start[node], s1 = row_start[node + 1];
    float ax = 0.f, ay = 0.f;
    for (int i = s0; i < s1; ++i) {
        int s = edge_src[i];
        unsigned int v = *(const unsigned int*)(X + (size_t)s * 128 + lane * 2);
        ax += bf_lo(v);
        ay += bf_hi(v);
    }
    int deg = s1 - s0;
    float inv = 1.0f / (float)(deg > 1 ? deg : 1);
    ax *= inv; ay *= inv;
    unsigned int p = (unsigned int)f2bf(ax) | ((unsigned int)f2bf(ay) << 16);
    *(unsigned int*)(mean + (size_t)node * 128 + lane * 2) = p;
}

// out[n,:] = mean_agg(P)[n,:] + R[n,:]   (P bf16 [N,128], R f32 [N,128], out f32)
__global__ __launch_bounds__(256) void agg2_kernel(
    const unsigned short* __restrict__ P, const float* __restrict__ R,
    const int* __restrict__ row_start, const int* __restrict__ edge_src,
    float* __restrict__ out) {
    int node = blockIdx.x * 4 + (threadIdx.x >> 6);
    int lane = threadIdx.x & 63;
    if (node >= NN) return;
    int s0 = row_start[node], s1 = row_start[node + 1];
    float ax = 0.f, ay = 0.f;
    for (int i = s0; i < s1; ++i) {
        int s = edge_src[i];
        unsigned int v = *(const unsigned int*)(P + (size_t)s * 128 + lane * 2);
        ax += bf_lo(v);
        ay += bf_hi(v);
    }
    int deg = s1 - s0;
    float inv = 1.0f / (float)(deg > 1 ? deg : 1);
    float2 r2 = *(const float2*)(R + (size_t)node * 128 + lane * 2);
    float2 o;
    o.x = ax * inv + r2.x;
    o.y = ay * inv + r2.y;
    *(float2*)(out + (size_t)node * 128 + lane * 2) = o;
}

// ---------------- bf16 MFMA GEMM ----------------
// C[m,n] = sum_k A[m,k] * B[n,k] (+bias) ; A = [A1 (K1 cols) || A2 (256-K1 cols)] bf16,
// B [256,256] bf16 row-major (n-major). K fixed = 256, OUT fixed = 256.
// cols < split  -> bf16 output outBF (ld=split), bias biasBF (nullable), optional relu
// cols >= split -> f32 output outF (ld=256-split), bias biasF
// Tile: 64 rows x 64 cols per block (4 waves: wave w -> cols w*16..w*16+15),
// K staged in 2 slices of 128. mfma_f32_16x16x32_bf16.
#define LDK 136  // 128 + 8 pad (row stride 272 B: 16B-aligned, +4-bank rotation/row)
__global__ __launch_bounds__(256) void gemm_mfma(
    const unsigned short* __restrict__ A1, const unsigned short* __restrict__ A2, int K1,
    const unsigned short* __restrict__ B,
    const float* __restrict__ biasBF, const float* __restrict__ biasF,
    unsigned short* __restrict__ outBF, float* __restrict__ outF,
    int N, int split, int reluBF) {
    __shared__ unsigned short As[64 * LDK];
    __shared__ unsigned short Bs[64 * LDK];
    int tid = threadIdx.x;
    int row0 = blockIdx.x * 64, col0 = blockIdx.y * 64;
    int w = tid >> 6, lane = tid & 63;
    int q = lane >> 4, l16 = lane & 15;

    f32x4 acc[4] = {{0.f, 0.f, 0.f, 0.f}, {0.f, 0.f, 0.f, 0.f},
                    {0.f, 0.f, 0.f, 0.f}, {0.f, 0.f, 0.f, 0.f}};
    const int K2 = 256 - K1;

    for (int ks = 0; ks < 2; ++ks) {
        int kbase = ks * 128;
        if (ks) __syncthreads();
        // stage A,B slice [*, kbase..kbase+127]; 64 rows x 16 groups of 8 bf16 (16B)
#pragma unroll
        for (int i = 0; i < 4; ++i) {
            int lin = tid + 256 * i;        // 0..1023
            int r = lin >> 4;               // 0..63
            int g = lin & 15;               // group
            int k = kbase + g * 8;
            // A
            uint4 av = make_uint4(0, 0, 0, 0);
            int grow = row0 + r;
            if (grow < N) {
                if (k < K1) av = *(const uint4*)(A1 + (size_t)grow * K1 + k);
                else        av = *(const uint4*)(A2 + (size_t)grow * K2 + (k - K1));
            }
            *(uint4*)&As[r * LDK + g * 8] = av;
            // B (col0+r always < 256)
            uint4 bv = *(const uint4*)(B + (size_t)(col0 + r) * 256 + k);
            *(uint4*)&Bs[r * LDK + g * 8] = bv;
        }
        __syncthreads();
#pragma unroll
        for (int k0 = 0; k0 < 128; k0 += 32) {
            bf16x8 bfrag = *(const bf16x8*)&Bs[(w * 16 + l16) * LDK + k0 + q * 8];
#pragma unroll
            for (int r = 0; r < 4; ++r) {
                bf16x8 afrag = *(const bf16x8*)&As[(r * 16 + l16) * LDK + k0 + q * 8];
                acc[r] = __builtin_amdgcn_mfma_f32_16x16x32_bf16(afrag, bfrag, acc[r], 0, 0, 0);
            }
        }
    }

    // epilogue: D col = lane&15, row = q*4 + reg  (per 16x16 tile r)
    int colg = col0 + w * 16 + l16;
    bool isBF = (colg < split);
    float bb = 0.f;
    if (isBF) { if (biasBF) bb = biasBF[colg]; }
    else      bb = biasF[colg - split];
#pragma unroll
    for (int r = 0; r < 4; ++r) {
#pragma unroll
        for (int reg = 0; reg < 4; ++reg) {
            int rowg = row0 + r * 16 + q * 4 + reg;
            if (rowg < N) {
                float v = acc[r][reg] + bb;
                if (isBF) {
                    if (reluBF) v = fmaxf(v, 0.f);
                    outBF[(size_t)rowg * split + colg] = f2bf(v);
                } else {
                    outF[(size_t)rowg * (256 - split) + (colg - split)] = v;
                }
            }
        }
    }
}

extern "C" void kernel_launch(void* const* d_in, const int* in_sizes, int n_in,
                              void* d_out, int out_size, void* d_ws, size_t ws_size,
                              hipStream_t stream) {
    const float* x    = (const float*)d_in[0];
    const int*   edges = (const int*)d_in[1];
    const float* W1_l = (const float*)d_in[2];
    const float* b1   = (const float*)d_in[3];
    const float* W1_r = (const float*)d_in[4];
    const float* W2_l = (const float*)d_in[5];
    const float* b2   = (const float*)d_in[6];
    const float* W2_r = (const float*)d_in[7];
    float* out = (float*)d_out;

    const int N = NN, E = NE;
    const int NB = (N + 255) / 256;   // 196 scan blocks
    auto al = [](size_t v) { return (v + 255) & ~(size_t)255; };
    char* ws = (char*)d_ws;
    size_t o = 0;
    int* flag      = (int*)(ws + o); o += 256;
    int* counts    = (int*)(ws + o); o += al((size_t)N * 4);
    int* partial   = (int*)(ws + o); o += al((size_t)N * 4);
    int* bsum      = (int*)(ws + o); o += al((size_t)NB * 4);
    int* boff      = (int*)(ws + o); o += al((size_t)(NB + 1) * 4);
    int* row_start = (int*)(ws + o); o += al((size_t)(N + 1) * 4);
    int* cursor    = (int*)(ws + o); o += al((size_t)N * 4);
    int* edge_src  = (int*)(ws + o); o += al((size_t)E * 4);
    unsigned short* x_bf  = (unsigned short*)(ws + o); o += al((size_t)N * 128 * 2);
    unsigned short* mean1 = (unsigned short*)(ws + o); o += al((size_t)N * 128 * 2);
    unsigned short* h_bf  = (unsigned short*)(ws + o); o += al((size_t)N * 256 * 2);
    unsigned short* P_bf  = (unsigned short*)(ws + o); o += al((size_t)N * 128 * 2);
    float*          R_f   = (float*)(ws + o);          o += al((size_t)N * 128 * 4);
    unsigned short* B1    = (unsigned short*)(ws + o); o += al((size_t)256 * 256 * 2);
    unsigned short* B2    = (unsigned short*)(ws + o); o += al((size_t)256 * 256 * 2);

    hipMemsetAsync(counts, 0, (size_t)N * 4, stream);
    detect_kernel<<<1, 256, 0, stream>>>(edges, flag);
    hist_kernel<<<(E + 255) / 256, 256, 0, stream>>>(edges, flag, counts, E);
    scan1_kernel<<<NB, 256, 0, stream>>>(counts, partial, bsum, N);
    scan2_kernel<<<1, 256, 0, stream>>>(bsum, boff, NB);
    scan3_kernel<<<NB, 256, 0, stream>>>(partial, boff, row_start, cursor, N, NB);
    fill_kernel<<<(E + 255) / 256, 256, 0, stream>>>(edges, flag, cursor, edge_src, E);

    cast_x_kernel<<<(N * 64 + 255) / 256, 256, 0, stream>>>(x, x_bf, N * 64);
    packB1_kernel<<<256, 256, 0, stream>>>(W1_l, W1_r, B1);
    packB2_kernel<<<256, 256, 0, stream>>>(W2_l, W2_r, B2);

    // layer 1: mean1 = agg(x_bf); h = relu([mean1||x_bf] @ B1^T + b1)  (bf16 out)
    agg1_kernel<<<(N + 3) / 4, 256, 0, stream>>>(x_bf, row_start, edge_src, mean1);
    {
        dim3 grid((N + 63) / 64, 4);
        gemm_mfma<<<grid, 256, 0, stream>>>(mean1, x_bf, 128, B1, b1, b1,
                                            h_bf, (float*)nullptr, N, 256, 1);
    }
    // layer 2: [P||R] = h @ B2^T ; P bf16 (cols<128, no bias), R f32 (+b2)
    {
        dim3 grid((N + 63) / 64, 4);
        gemm_mfma<<<grid, 256, 0, stream>>>(h_bf, h_bf, 256, B2, (float*)nullptr, b2,
                                            P_bf, R_f, N, 128, 0);
    }
    // out = agg(P) + R
    agg2_kernel<<<(N + 3) / 4, 256, 0, stream>>>(P_bf, R_f, row_start, edge_src, out);
}

// Round 3
// 327.622 us; speedup vs baseline: 2.3247x; 1.2657x over previous
//
#include <hip/hip_runtime.h>
#include <stdint.h>

#define NN 50000
#define NE 800000
// layer1: in=128 hid=256; layer2: in=256 out=128
// Layer-2 restructured: out = mean_agg(h @ W2_l^T) + (h @ W2_r^T + b2)

typedef __bf16 bf16x8 __attribute__((ext_vector_type(8)));
typedef float  f32x4  __attribute__((ext_vector_type(4)));

__device__ __forceinline__ unsigned short f2bf(float f) {
    unsigned int u = __float_as_uint(f);
    unsigned int r = (u + 0x7fffu + ((u >> 16) & 1u)) >> 16;   // RNE
    return (unsigned short)r;
}
__device__ __forceinline__ float bf_lo(unsigned int v) { return __uint_as_float(v << 16); }
__device__ __forceinline__ float bf_hi(unsigned int v) { return __uint_as_float(v & 0xffff0000u); }

// ---------------- edge dtype detector (int64 vs int32 storage) ----------------
__global__ void detect_kernel(const int* __restrict__ edges, int* __restrict__ flag) {
    __shared__ int nz;
    if (threadIdx.x == 0) nz = 0;
    __syncthreads();
    for (int i = threadIdx.x; i < 512; i += blockDim.x)
        if (edges[2 * i + 1] != 0) atomicOr(&nz, 1);
    __syncthreads();
    if (threadIdx.x == 0) *flag = nz ? 0 : 1;  // 1 => int64 storage
}

// ---------------- CSR build ----------------
__global__ void hist_kernel(const int* __restrict__ edges, const int* __restrict__ flag,
                            int* __restrict__ counts, int E) {
    int f = *flag;
    int e = blockIdx.x * blockDim.x + threadIdx.x;
    if (e < E) atomicAdd(&counts[edges[(size_t)(E + e) << f]], 1);
}

__global__ void scan1_kernel(const int* __restrict__ counts, int* __restrict__ partial,
                             int* __restrict__ bsum, int N) {
    __shared__ int buf[256];
    int tid = threadIdx.x;
    int g = blockIdx.x * 256 + tid;
    int v = (g < N) ? counts[g] : 0;
    buf[tid] = v;
    __syncthreads();
    for (int off = 1; off < 256; off <<= 1) {
        int t = (tid >= off) ? buf[tid - off] : 0;
        __syncthreads();
        buf[tid] += t;
        __syncthreads();
    }
    if (g < N) partial[g] = buf[tid] - v;
    if (tid == 255) bsum[blockIdx.x] = buf[255];
}

__global__ void scan2_kernel(const int* __restrict__ bsum, int* __restrict__ boff, int nb) {
    __shared__ int buf[256];
    int tid = threadIdx.x;
    int v = (tid < nb) ? bsum[tid] : 0;
    buf[tid] = v;
    __syncthreads();
    for (int off = 1; off < 256; off <<= 1) {
        int t = (tid >= off) ? buf[tid - off] : 0;
        __syncthreads();
        buf[tid] += t;
        __syncthreads();
    }
    if (tid < nb) boff[tid] = buf[tid] - v;
    if (tid == 0) boff[nb] = buf[255];
}

__global__ void scan3_kernel(const int* __restrict__ partial, const int* __restrict__ boff,
                             int* __restrict__ row_start, int* __restrict__ cursor,
                             int N, int nb) {
    int g = blockIdx.x * 256 + threadIdx.x;
    if (g < N) {
        int v = partial[g] + boff[g >> 8];
        row_start[g] = v;
        cursor[g] = v;
    }
    if (g == 0) row_start[N] = boff[nb];
}

__global__ void fill_kernel(const int* __restrict__ edges, const int* __restrict__ flag,
                            int* __restrict__ cursor, int* __restrict__ edge_src, int E) {
    int f = *flag;
    int e = blockIdx.x * blockDim.x + threadIdx.x;
    if (e < E) {
        int s = edges[(size_t)e << f];
        int d = edges[(size_t)(E + e) << f];
        edge_src[atomicAdd(&cursor[d], 1)] = s;
    }
}

// ---------------- casts / weight packing ----------------
__global__ void cast_x_kernel(const float* __restrict__ in, unsigned short* __restrict__ out, int n2) {
    int i = blockIdx.x * blockDim.x + threadIdx.x;
    if (i < n2) {
        float2 v = *(const float2*)(in + 2 * (size_t)i);
        unsigned int p = (unsigned int)f2bf(v.x) | ((unsigned int)f2bf(v.y) << 16);
        *(unsigned int*)(out + 2 * (size_t)i) = p;
    }
}

__global__ void packB1_kernel(const float* __restrict__ Wl, const float* __restrict__ Wr,
                              unsigned short* __restrict__ B) {
    int idx = blockIdx.x * 256 + threadIdx.x;
    int o = idx >> 8, k = idx & 255;
    float v = (k < 128) ? Wl[o * 128 + k] : Wr[o * 128 + (k - 128)];
    B[idx] = f2bf(v);
}
__global__ void packB2_kernel(const float* __restrict__ Wl, const float* __restrict__ Wr,
                              unsigned short* __restrict__ B) {
    int idx = blockIdx.x * 256 + threadIdx.x;
    int o = idx >> 8, k = idx & 255;
    float v = (o < 128) ? Wl[o * 256 + k] : Wr[(o - 128) * 256 + k];
    B[idx] = f2bf(v);
}

// ---------------- mean aggregation, width-128 bf16 rows ----------------
// 1 wave per node; scalar loop bounds (s_load edge indices), 8x unrolled gathers for ILP.
__global__ __launch_bounds__(256) void agg1_kernel(
    const unsigned short* __restrict__ X, const int* __restrict__ row_start,
    const int* __restrict__ edge_src, unsigned short* __restrict__ mean) {
    int node = blockIdx.x * 4 + (threadIdx.x >> 6);
    int lane = threadIdx.x & 63;
    if (node >= NN) return;
    int s0 = __builtin_amdgcn_readfirstlane(row_start[node]);
    int s1 = __builtin_amdgcn_readfirstlane(row_start[node + 1]);
    float ax = 0.f, ay = 0.f;
    int i = s0;
    for (; i + 8 <= s1; i += 8) {
        unsigned int v[8];
#pragma unroll
        for (int u = 0; u < 8; ++u) {
            int s = edge_src[i + u];
            v[u] = *(const unsigned int*)(X + ((size_t)s << 7) + lane * 2);
        }
#pragma unroll
        for (int u = 0; u < 8; ++u) { ax += bf_lo(v[u]); ay += bf_hi(v[u]); }
    }
    for (; i < s1; ++i) {
        int s = edge_src[i];
        unsigned int v = *(const unsigned int*)(X + ((size_t)s << 7) + lane * 2);
        ax += bf_lo(v); ay += bf_hi(v);
    }
    int deg = s1 - s0;
    float inv = 1.0f / (float)(deg > 1 ? deg : 1);
    ax *= inv; ay *= inv;
    unsigned int p = (unsigned int)f2bf(ax) | ((unsigned int)f2bf(ay) << 16);
    *(unsigned int*)(mean + ((size_t)node << 7) + lane * 2) = p;
}

// out[n,:] = mean_agg(P)[n,:] + R[n,:]
__global__ __launch_bounds__(256) void agg2_kernel(
    const unsigned short* __restrict__ P, const float* __restrict__ R,
    const int* __restrict__ row_start, const int* __restrict__ edge_src,
    float* __restrict__ out) {
    int node = blockIdx.x * 4 + (threadIdx.x >> 6);
    int lane = threadIdx.x & 63;
    if (node >= NN) return;
    int s0 = __builtin_amdgcn_readfirstlane(row_start[node]);
    int s1 = __builtin_amdgcn_readfirstlane(row_start[node + 1]);
    float ax = 0.f, ay = 0.f;
    int i = s0;
    for (; i + 8 <= s1; i += 8) {
        unsigned int v[8];
#pragma unroll
        for (int u = 0; u < 8; ++u) {
            int s = edge_src[i + u];
            v[u] = *(const unsigned int*)(P + ((size_t)s << 7) + lane * 2);
        }
#pragma unroll
        for (int u = 0; u < 8; ++u) { ax += bf_lo(v[u]); ay += bf_hi(v[u]); }
    }
    for (; i < s1; ++i) {
        int s = edge_src[i];
        unsigned int v = *(const unsigned int*)(P + ((size_t)s << 7) + lane * 2);
        ax += bf_lo(v); ay += bf_hi(v);
    }
    int deg = s1 - s0;
    float inv = 1.0f / (float)(deg > 1 ? deg : 1);
    float2 r2 = *(const float2*)(R + ((size_t)node << 7) + lane * 2);
    float2 o;
    o.x = ax * inv + r2.x;
    o.y = ay * inv + r2.y;
    *(float2*)(out + ((size_t)node << 7) + lane * 2) = o;
}

// ---------------- bf16 MFMA GEMM: 64 rows x 256 cols per block ----------------
// C[m,n] = sum_k A[m,k]*B[n,k] (+bias); A=[A1(K1)||A2(256-K1)] bf16, B[256][256] bf16.
// A read ONCE per element (full OUT covered by one block). 4 waves, wave w -> cols
// [w*64, w*64+64); each wave 4x4 tiles of 16x16 via mfma_f32_16x16x32_bf16.
// K staged in 4 slices of 64. LDS row stride 72 (=64+8 bf16, 144 B): <=2-way conflicts.
#define LDK 72
__global__ __launch_bounds__(256) void gemm_mfma(
    const unsigned short* __restrict__ A1, const unsigned short* __restrict__ A2, int K1,
    const unsigned short* __restrict__ B,
    const float* __restrict__ biasBF, const float* __restrict__ biasF,
    unsigned short* __restrict__ outBF, float* __restrict__ outF,
    int N, int split, int reluBF) {
    __shared__ unsigned short As[64 * LDK];    // 9.0 KB
    __shared__ unsigned short Bs[256 * LDK];   // 36.0 KB
    int tid = threadIdx.x;
    int row0 = blockIdx.x * 64;
    int w = tid >> 6, lane = tid & 63;
    int q = lane >> 4, l16 = lane & 15;

    f32x4 acc[4][4];
#pragma unroll
    for (int r = 0; r < 4; ++r)
#pragma unroll
        for (int c = 0; c < 4; ++c) acc[r][c] = (f32x4){0.f, 0.f, 0.f, 0.f};
    const int K2 = 256 - K1;

    for (int ks = 0; ks < 4; ++ks) {
        int kbase = ks * 64;
        if (ks) __syncthreads();
        // stage A: 64 rows x 8 groups of 8 bf16 -> 512 uint4
#pragma unroll
        for (int i = 0; i < 2; ++i) {
            int lin = tid + 256 * i;
            int r = lin >> 3, g = lin & 7;
            int k = kbase + g * 8;
            uint4 av = make_uint4(0, 0, 0, 0);
            int grow = row0 + r;
            if (grow < N) {
                if (k < K1) av = *(const uint4*)(A1 + (size_t)grow * K1 + k);
                else        av = *(const uint4*)(A2 + (size_t)grow * K2 + (k - K1));
            }
            *(uint4*)&As[r * LDK + g * 8] = av;
        }
        // stage B: 256 rows x 8 groups -> 2048 uint4
#pragma unroll
        for (int i = 0; i < 8; ++i) {
            int lin = tid + 256 * i;
            int n = lin >> 3, g = lin & 7;
            int k = kbase + g * 8;
            *(uint4*)&Bs[n * LDK + g * 8] = *(const uint4*)(B + ((size_t)n << 8) + k);
        }
        __syncthreads();
#pragma unroll
        for (int k0 = 0; k0 < 64; k0 += 32) {
            bf16x8 bfrag[4], afrag[4];
#pragma unroll
            for (int c = 0; c < 4; ++c)
                bfrag[c] = *(const bf16x8*)&Bs[(w * 64 + c * 16 + l16) * LDK + k0 + q * 8];
#pragma unroll
            for (int r = 0; r < 4; ++r)
                afrag[r] = *(const bf16x8*)&As[(r * 16 + l16) * LDK + k0 + q * 8];
#pragma unroll
            for (int r = 0; r < 4; ++r)
#pragma unroll
                for (int c = 0; c < 4; ++c)
                    acc[r][c] = __builtin_amdgcn_mfma_f32_16x16x32_bf16(afrag[r], bfrag[c], acc[r][c], 0, 0, 0);
        }
    }

    // epilogue: D col = lane&15, row = q*4 + reg
#pragma unroll
    for (int c = 0; c < 4; ++c) {
        int colg = w * 64 + c * 16 + l16;
        bool isBF = (colg < split);
        float bb = 0.f;
        if (isBF) { if (biasBF) bb = biasBF[colg]; }
        else      bb = biasF[colg - split];
#pragma unroll
        for (int r = 0; r < 4; ++r) {
#pragma unroll
            for (int reg = 0; reg < 4; ++reg) {
                int rowg = row0 + r * 16 + q * 4 + reg;
                if (rowg < N) {
                    float v = acc[r][c][reg] + bb;
                    if (isBF) {
                        if (reluBF) v = fmaxf(v, 0.f);
                        outBF[(size_t)rowg * split + colg] = f2bf(v);
                    } else {
                        outF[(size_t)rowg * (256 - split) + (colg - split)] = v;
                    }
                }
            }
        }
    }
}

extern "C" void kernel_launch(void* const* d_in, const int* in_sizes, int n_in,
                              void* d_out, int out_size, void* d_ws, size_t ws_size,
                              hipStream_t stream) {
    const float* x    = (const float*)d_in[0];
    const int*   edges = (const int*)d_in[1];
    const float* W1_l = (const float*)d_in[2];
    const float* b1   = (const float*)d_in[3];
    const float* W1_r = (const float*)d_in[4];
    const float* W2_l = (const float*)d_in[5];
    const float* b2   = (const float*)d_in[6];
    const float* W2_r = (const float*)d_in[7];
    float* out = (float*)d_out;

    const int N = NN, E = NE;
    const int NB = (N + 255) / 256;
    auto al = [](size_t v) { return (v + 255) & ~(size_t)255; };
    char* ws = (char*)d_ws;
    size_t o = 0;
    int* flag      = (int*)(ws + o); o += 256;
    int* counts    = (int*)(ws + o); o += al((size_t)N * 4);
    int* partial   = (int*)(ws + o); o += al((size_t)N * 4);
    int* bsum      = (int*)(ws + o); o += al((size_t)NB * 4);
    int* boff      = (int*)(ws + o); o += al((size_t)(NB + 1) * 4);
    int* row_start = (int*)(ws + o); o += al((size_t)(N + 1) * 4);
    int* cursor    = (int*)(ws + o); o += al((size_t)N * 4);
    int* edge_src  = (int*)(ws + o); o += al((size_t)E * 4);
    unsigned short* x_bf  = (unsigned short*)(ws + o); o += al((size_t)N * 128 * 2);
    unsigned short* mean1 = (unsigned short*)(ws + o); o += al((size_t)N * 128 * 2);
    unsigned short* h_bf  = (unsigned short*)(ws + o); o += al((size_t)N * 256 * 2);
    unsigned short* P_bf  = (unsigned short*)(ws + o); o += al((size_t)N * 128 * 2);
    float*          R_f   = (float*)(ws + o);          o += al((size_t)N * 128 * 4);
    unsigned short* B1    = (unsigned short*)(ws + o); o += al((size_t)256 * 256 * 2);
    unsigned short* B2    = (unsigned short*)(ws + o); o += al((size_t)256 * 256 * 2);

    hipMemsetAsync(counts, 0, (size_t)N * 4, stream);
    detect_kernel<<<1, 256, 0, stream>>>(edges, flag);
    hist_kernel<<<(E + 255) / 256, 256, 0, stream>>>(edges, flag, counts, E);
    scan1_kernel<<<NB, 256, 0, stream>>>(counts, partial, bsum, N);
    scan2_kernel<<<1, 256, 0, stream>>>(bsum, boff, NB);
    scan3_kernel<<<NB, 256, 0, stream>>>(partial, boff, row_start, cursor, N, NB);
    fill_kernel<<<(E + 255) / 256, 256, 0, stream>>>(edges, flag, cursor, edge_src, E);

    cast_x_kernel<<<(N * 64 + 255) / 256, 256, 0, stream>>>(x, x_bf, N * 64);
    packB1_kernel<<<256, 256, 0, stream>>>(W1_l, W1_r, B1);
    packB2_kernel<<<256, 256, 0, stream>>>(W2_l, W2_r, B2);

    // layer 1: mean1 = agg(x_bf); h = relu([mean1||x_bf] @ B1^T + b1) (bf16)
    agg1_kernel<<<(N + 3) / 4, 256, 0, stream>>>(x_bf, row_start, edge_src, mean1);
    gemm_mfma<<<(N + 63) / 64, 256, 0, stream>>>(mean1, x_bf, 128, B1, b1, b1,
                                                 h_bf, (float*)nullptr, N, 256, 1);
    // layer 2: [P||R] = h @ B2^T ; P bf16 (no bias), R f32 (+b2)
    gemm_mfma<<<(N + 63) / 64, 256, 0, stream>>>(h_bf, h_bf, 256, B2, (float*)nullptr, b2,
                                                 P_bf, R_f, N, 128, 0);
    // out = agg(P) + R
    agg2_kernel<<<(N + 3) / 4, 256, 0, stream>>>(P_bf, R_f, row_start, edge_src, out);
}

// Round 4
// 318.331 us; speedup vs baseline: 2.3925x; 1.0292x over previous
//
#include <hip/hip_runtime.h>
#include <stdint.h>

#define NN 50000
#define NE 800000
// layer1: in=128 hid=256; layer2: in=256 out=128
// Layer-2 restructured: out = mean_agg(h @ W2_l^T) + (h @ W2_r^T + b2)

typedef __bf16 bf16x8 __attribute__((ext_vector_type(8)));
typedef float  f32x4  __attribute__((ext_vector_type(4)));

__device__ __forceinline__ unsigned short f2bf(float f) {
    unsigned int u = __float_as_uint(f);
    unsigned int r = (u + 0x7fffu + ((u >> 16) & 1u)) >> 16;   // RNE
    return (unsigned short)r;
}
__device__ __forceinline__ float bf_lo(unsigned int v) { return __uint_as_float(v << 16); }
__device__ __forceinline__ float bf_hi(unsigned int v) { return __uint_as_float(v & 0xffff0000u); }

// ---------------- edge dtype detector (int64 vs int32 storage) ----------------
__global__ void detect_kernel(const int* __restrict__ edges, int* __restrict__ flag) {
    __shared__ int nz;
    if (threadIdx.x == 0) nz = 0;
    __syncthreads();
    for (int i = threadIdx.x; i < 512; i += blockDim.x)
        if (edges[2 * i + 1] != 0) atomicOr(&nz, 1);
    __syncthreads();
    if (threadIdx.x == 0) *flag = nz ? 0 : 1;  // 1 => int64 storage
}

// ---------------- CSR build ----------------
// 8 edges per thread: 8 independent atomic chains in flight per lane (latency hiding).
__global__ __launch_bounds__(256) void hist_kernel(const int* __restrict__ edges,
                                                   const int* __restrict__ flag,
                                                   int* __restrict__ counts, int E) {
    int f = *flag;
    int base = (blockIdx.x * 256 + threadIdx.x) * 8;
    if (base + 8 <= E) {
        int d[8];
#pragma unroll
        for (int u = 0; u < 8; ++u) d[u] = edges[(size_t)(E + base + u) << f];
#pragma unroll
        for (int u = 0; u < 8; ++u) atomicAdd(&counts[d[u]], 1);
    } else {
        for (int e = base; e < E; ++e)
            atomicAdd(&counts[edges[(size_t)(E + e) << f]], 1);
    }
}

__global__ void scan1_kernel(const int* __restrict__ counts, int* __restrict__ partial,
                             int* __restrict__ bsum, int N) {
    __shared__ int buf[256];
    int tid = threadIdx.x;
    int g = blockIdx.x * 256 + tid;
    int v = (g < N) ? counts[g] : 0;
    buf[tid] = v;
    __syncthreads();
    for (int off = 1; off < 256; off <<= 1) {
        int t = (tid >= off) ? buf[tid - off] : 0;
        __syncthreads();
        buf[tid] += t;
        __syncthreads();
    }
    if (g < N) partial[g] = buf[tid] - v;
    if (tid == 255) bsum[blockIdx.x] = buf[255];
}

__global__ void scan2_kernel(const int* __restrict__ bsum, int* __restrict__ boff, int nb) {
    __shared__ int buf[256];
    int tid = threadIdx.x;
    int v = (tid < nb) ? bsum[tid] : 0;
    buf[tid] = v;
    __syncthreads();
    for (int off = 1; off < 256; off <<= 1) {
        int t = (tid >= off) ? buf[tid - off] : 0;
        __syncthreads();
        buf[tid] += t;
        __syncthreads();
    }
    if (tid < nb) boff[tid] = buf[tid] - v;
    if (tid == 0) boff[nb] = buf[255];
}

__global__ void scan3_kernel(const int* __restrict__ partial, const int* __restrict__ boff,
                             int* __restrict__ row_start, int* __restrict__ cursor,
                             int N, int nb) {
    int g = blockIdx.x * 256 + threadIdx.x;
    if (g < N) {
        int v = partial[g] + boff[g >> 8];
        row_start[g] = v;
        cursor[g] = v;
    }
    if (g == 0) row_start[N] = boff[nb];
}

// 8 edges per thread, atomics + dependent scatter stores all pipelined.
__global__ __launch_bounds__(256) void fill_kernel(const int* __restrict__ edges,
                                                   const int* __restrict__ flag,
                                                   int* __restrict__ cursor,
                                                   int* __restrict__ edge_src, int E) {
    int f = *flag;
    int base = (blockIdx.x * 256 + threadIdx.x) * 8;
    if (base + 8 <= E) {
        int s[8], d[8], pos[8];
#pragma unroll
        for (int u = 0; u < 8; ++u) {
            s[u] = edges[(size_t)(base + u) << f];
            d[u] = edges[(size_t)(E + base + u) << f];
        }
#pragma unroll
        for (int u = 0; u < 8; ++u) pos[u] = atomicAdd(&cursor[d[u]], 1);
#pragma unroll
        for (int u = 0; u < 8; ++u) edge_src[pos[u]] = s[u];
    } else {
        for (int e = base; e < E; ++e) {
            int s0 = edges[(size_t)e << f];
            int d0 = edges[(size_t)(E + e) << f];
            edge_src[atomicAdd(&cursor[d0], 1)] = s0;
        }
    }
}

// ---------------- casts / weight packing ----------------
__global__ void cast_x_kernel(const float* __restrict__ in, unsigned short* __restrict__ out, int n2) {
    int i = blockIdx.x * blockDim.x + threadIdx.x;
    if (i < n2) {
        float2 v = *(const float2*)(in + 2 * (size_t)i);
        unsigned int p = (unsigned int)f2bf(v.x) | ((unsigned int)f2bf(v.y) << 16);
        *(unsigned int*)(out + 2 * (size_t)i) = p;
    }
}

// B1[o][k]: k<128 -> W1_l[o,k] else W1_r[o,k-128].  B2[o][k]: o<128 -> W2_l[o,k] else W2_r[o-128,k].
__global__ void packB_kernel(const float* __restrict__ W1l, const float* __restrict__ W1r,
                             const float* __restrict__ W2l, const float* __restrict__ W2r,
                             unsigned short* __restrict__ B1, unsigned short* __restrict__ B2) {
    int idx = blockIdx.x * 256 + threadIdx.x;   // grid = 512 blocks
    if (idx < 65536) {
        int o = idx >> 8, k = idx & 255;
        float v = (k < 128) ? W1l[o * 128 + k] : W1r[o * 128 + (k - 128)];
        B1[idx] = f2bf(v);
    } else {
        int j = idx - 65536;
        int o = j >> 8, k = j & 255;
        float v = (o < 128) ? W2l[o * 256 + k] : W2r[(o - 128) * 256 + k];
        B2[j] = f2bf(v);
    }
}

// ---------------- mean aggregation, width-128 bf16 rows ----------------
// Half-wave (32 lanes) per node: 2 independent gather chains per wave, x8 unroll
// -> 16 outstanding gathers/wave. Row = 32 lanes x 8 B = 256 B coalesced.
__global__ __launch_bounds__(256) void agg1_kernel(
    const unsigned short* __restrict__ X, const int* __restrict__ row_start,
    const int* __restrict__ edge_src, unsigned short* __restrict__ mean) {
    int node = blockIdx.x * 8 + (threadIdx.x >> 5);
    int l = threadIdx.x & 31;
    if (node >= NN) return;
    int s0 = row_start[node], s1 = row_start[node + 1];
    float a0 = 0.f, a1 = 0.f, a2 = 0.f, a3 = 0.f;
    int i = s0;
    for (; i + 8 <= s1; i += 8) {
        uint2 v[8];
#pragma unroll
        for (int u = 0; u < 8; ++u) {
            int s = edge_src[i + u];
            v[u] = *(const uint2*)(X + ((size_t)s << 7) + l * 4);
        }
#pragma unroll
        for (int u = 0; u < 8; ++u) {
            a0 += bf_lo(v[u].x); a1 += bf_hi(v[u].x);
            a2 += bf_lo(v[u].y); a3 += bf_hi(v[u].y);
        }
    }
    for (; i < s1; ++i) {
        int s = edge_src[i];
        uint2 v = *(const uint2*)(X + ((size_t)s << 7) + l * 4);
        a0 += bf_lo(v.x); a1 += bf_hi(v.x);
        a2 += bf_lo(v.y); a3 += bf_hi(v.y);
    }
    int deg = s1 - s0;
    float inv = 1.0f / (float)(deg > 1 ? deg : 1);
    uint2 p;
    p.x = (unsigned int)f2bf(a0 * inv) | ((unsigned int)f2bf(a1 * inv) << 16);
    p.y = (unsigned int)f2bf(a2 * inv) | ((unsigned int)f2bf(a3 * inv) << 16);
    *(uint2*)(mean + ((size_t)node << 7) + l * 4) = p;
}

// out[n,:] = mean_agg(P)[n,:] + R[n,:]   (P bf16 [N,128], R f32 [N,128], out f32)
__global__ __launch_bounds__(256) void agg2_kernel(
    const unsigned short* __restrict__ P, const float* __restrict__ R,
    const int* __restrict__ row_start, const int* __restrict__ edge_src,
    float* __restrict__ out) {
    int node = blockIdx.x * 8 + (threadIdx.x >> 5);
    int l = threadIdx.x & 31;
    if (node >= NN) return;
    int s0 = row_start[node], s1 = row_start[node + 1];
    float a0 = 0.f, a1 = 0.f, a2 = 0.f, a3 = 0.f;
    int i = s0;
    for (; i + 8 <= s1; i += 8) {
        uint2 v[8];
#pragma unroll
        for (int u = 0; u < 8; ++u) {
            int s = edge_src[i + u];
            v[u] = *(const uint2*)(P + ((size_t)s << 7) + l * 4);
        }
#pragma unroll
        for (int u = 0; u < 8; ++u) {
            a0 += bf_lo(v[u].x); a1 += bf_hi(v[u].x);
            a2 += bf_lo(v[u].y); a3 += bf_hi(v[u].y);
        }
    }
    for (; i < s1; ++i) {
        int s = edge_src[i];
        uint2 v = *(const uint2*)(P + ((size_t)s << 7) + l * 4);
        a0 += bf_lo(v.x); a1 += bf_hi(v.x);
        a2 += bf_lo(v.y); a3 += bf_hi(v.y);
    }
    int deg = s1 - s0;
    float inv = 1.0f / (float)(deg > 1 ? deg : 1);
    float4 r4 = *(const float4*)(R + ((size_t)node << 7) + l * 4);
    float4 o;
    o.x = a0 * inv + r4.x;
    o.y = a1 * inv + r4.y;
    o.z = a2 * inv + r4.z;
    o.w = a3 * inv + r4.w;
    *(float4*)(out + ((size_t)node << 7) + l * 4) = o;
}

// ---------------- bf16 MFMA GEMM: 64 rows x 256 cols per block ----------------
#define LDK 72
__global__ __launch_bounds__(256) void gemm_mfma(
    const unsigned short* __restrict__ A1, const unsigned short* __restrict__ A2, int K1,
    const unsigned short* __restrict__ B,
    const float* __restrict__ biasBF, const float* __restrict__ biasF,
    unsigned short* __restrict__ outBF, float* __restrict__ outF,
    int N, int split, int reluBF) {
    __shared__ unsigned short As[64 * LDK];    // 9.0 KB
    __shared__ unsigned short Bs[256 * LDK];   // 36.0 KB
    int tid = threadIdx.x;
    int row0 = blockIdx.x * 64;
    int w = tid >> 6, lane = tid & 63;
    int q = lane >> 4, l16 = lane & 15;

    f32x4 acc[4][4];
#pragma unroll
    for (int r = 0; r < 4; ++r)
#pragma unroll
        for (int c = 0; c < 4; ++c) acc[r][c] = (f32x4){0.f, 0.f, 0.f, 0.f};
    const int K2 = 256 - K1;

    for (int ks = 0; ks < 4; ++ks) {
        int kbase = ks * 64;
        if (ks) __syncthreads();
#pragma unroll
        for (int i = 0; i < 2; ++i) {
            int lin = tid + 256 * i;
            int r = lin >> 3, g = lin & 7;
            int k = kbase + g * 8;
            uint4 av = make_uint4(0, 0, 0, 0);
            int grow = row0 + r;
            if (grow < N) {
                if (k < K1) av = *(const uint4*)(A1 + (size_t)grow * K1 + k);
                else        av = *(const uint4*)(A2 + (size_t)grow * K2 + (k - K1));
            }
            *(uint4*)&As[r * LDK + g * 8] = av;
        }
#pragma unroll
        for (int i = 0; i < 8; ++i) {
            int lin = tid + 256 * i;
            int n = lin >> 3, g = lin & 7;
            int k = kbase + g * 8;
            *(uint4*)&Bs[n * LDK + g * 8] = *(const uint4*)(B + ((size_t)n << 8) + k);
        }
        __syncthreads();
#pragma unroll
        for (int k0 = 0; k0 < 64; k0 += 32) {
            bf16x8 bfrag[4], afrag[4];
#pragma unroll
            for (int c = 0; c < 4; ++c)
                bfrag[c] = *(const bf16x8*)&Bs[(w * 64 + c * 16 + l16) * LDK + k0 + q * 8];
#pragma unroll
            for (int r = 0; r < 4; ++r)
                afrag[r] = *(const bf16x8*)&As[(r * 16 + l16) * LDK + k0 + q * 8];
#pragma unroll
            for (int r = 0; r < 4; ++r)
#pragma unroll
                for (int c = 0; c < 4; ++c)
                    acc[r][c] = __builtin_amdgcn_mfma_f32_16x16x32_bf16(afrag[r], bfrag[c], acc[r][c], 0, 0, 0);
        }
    }

    // epilogue: D col = lane&15, row = q*4 + reg
#pragma unroll
    for (int c = 0; c < 4; ++c) {
        int colg = w * 64 + c * 16 + l16;
        bool isBF = (colg < split);
        float bb = 0.f;
        if (isBF) { if (biasBF) bb = biasBF[colg]; }
        else      bb = biasF[colg - split];
#pragma unroll
        for (int r = 0; r < 4; ++r) {
#pragma unroll
            for (int reg = 0; reg < 4; ++reg) {
                int rowg = row0 + r * 16 + q * 4 + reg;
                if (rowg < N) {
                    float v = acc[r][c][reg] + bb;
                    if (isBF) {
                        if (reluBF) v = fmaxf(v, 0.f);
                        outBF[(size_t)rowg * split + colg] = f2bf(v);
                    } else {
                        outF[(size_t)rowg * (256 - split) + (colg - split)] = v;
                    }
                }
            }
        }
    }
}

extern "C" void kernel_launch(void* const* d_in, const int* in_sizes, int n_in,
                              void* d_out, int out_size, void* d_ws, size_t ws_size,
                              hipStream_t stream) {
    const float* x    = (const float*)d_in[0];
    const int*   edges = (const int*)d_in[1];
    const float* W1_l = (const float*)d_in[2];
    const float* b1   = (const float*)d_in[3];
    const float* W1_r = (const float*)d_in[4];
    const float* W2_l = (const float*)d_in[5];
    const float* b2   = (const float*)d_in[6];
    const float* W2_r = (const float*)d_in[7];
    float* out = (float*)d_out;

    const int N = NN, E = NE;
    const int NB = (N + 255) / 256;
    auto al = [](size_t v) { return (v + 255) & ~(size_t)255; };
    char* ws = (char*)d_ws;
    size_t o = 0;
    int* flag      = (int*)(ws + o); o += 256;
    int* counts    = (int*)(ws + o); o += al((size_t)N * 4);
    int* partial   = (int*)(ws + o); o += al((size_t)N * 4);
    int* bsum      = (int*)(ws + o); o += al((size_t)NB * 4);
    int* boff      = (int*)(ws + o); o += al((size_t)(NB + 1) * 4);
    int* row_start = (int*)(ws + o); o += al((size_t)(N + 1) * 4);
    int* cursor    = (int*)(ws + o); o += al((size_t)N * 4);
    int* edge_src  = (int*)(ws + o); o += al((size_t)E * 4);
    unsigned short* x_bf  = (unsigned short*)(ws + o); o += al((size_t)N * 128 * 2);
    unsigned short* mean1 = (unsigned short*)(ws + o); o += al((size_t)N * 128 * 2);
    unsigned short* h_bf  = (unsigned short*)(ws + o); o += al((size_t)N * 256 * 2);
    unsigned short* P_bf  = (unsigned short*)(ws + o); o += al((size_t)N * 128 * 2);
    float*          R_f   = (float*)(ws + o);          o += al((size_t)N * 128 * 4);
    unsigned short* B1    = (unsigned short*)(ws + o); o += al((size_t)256 * 256 * 2);
    unsigned short* B2    = (unsigned short*)(ws + o); o += al((size_t)256 * 256 * 2);

    const int EB = (E / 8 + 255) / 256;   // 391 blocks, 8 edges/thread
    hipMemsetAsync(counts, 0, (size_t)N * 4, stream);
    detect_kernel<<<1, 256, 0, stream>>>(edges, flag);
    hist_kernel<<<EB, 256, 0, stream>>>(edges, flag, counts, E);
    scan1_kernel<<<NB, 256, 0, stream>>>(counts, partial, bsum, N);
    scan2_kernel<<<1, 256, 0, stream>>>(bsum, boff, NB);
    scan3_kernel<<<NB, 256, 0, stream>>>(partial, boff, row_start, cursor, N, NB);
    fill_kernel<<<EB, 256, 0, stream>>>(edges, flag, cursor, edge_src, E);

    cast_x_kernel<<<(N * 64 + 255) / 256, 256, 0, stream>>>(x, x_bf, N * 64);
    packB_kernel<<<512, 256, 0, stream>>>(W1_l, W1_r, W2_l, W2_r, B1, B2);

    // layer 1: mean1 = agg(x_bf); h = relu([mean1||x_bf] @ B1^T + b1) (bf16)
    agg1_kernel<<<(N + 7) / 8, 256, 0, stream>>>(x_bf, row_start, edge_src, mean1);
    gemm_mfma<<<(N + 63) / 64, 256, 0, stream>>>(mean1, x_bf, 128, B1, b1, b1,
                                                 h_bf, (float*)nullptr, N, 256, 1);
    // layer 2: [P||R] = h @ B2^T ; P bf16 (no bias), R f32 (+b2)
    gemm_mfma<<<(N + 63) / 64, 256, 0, stream>>>(h_bf, h_bf, 256, B2, (float*)nullptr, b2,
                                                 P_bf, R_f, N, 128, 0);
    // out = agg(P) + R
    agg2_kernel<<<(N + 7) / 8, 256, 0, stream>>>(P_bf, R_f, row_start, edge_src, out);
}